// Round 18
// baseline (98.609 us; speedup 1.0000x reference)
//
#include <hip/hip_runtime.h>
#include <hip/hip_bf16.h>
#include <math.h>

#define BN_EPS_F 1e-5f

typedef __attribute__((ext_vector_type(8))) short short8v;   // 8 bf16 = 4 VGPR
typedef __attribute__((ext_vector_type(4))) float floatx4;   // MFMA C/D

// split fp32 -> bf16 hi + bf16 lo  (x ~= hi + lo, rel err ~2^-17)
__device__ __forceinline__ void split2(float x, short& h, short& l) {
    __hip_bfloat16 bh = __float2bfloat16(x);
    float hf = __bfloat162float(bh);
    __hip_bfloat16 bl = __float2bfloat16(x - hf);
    h = __builtin_bit_cast(short, bh);
    l = __builtin_bit_cast(short, bl);
}

// ---------------------------------------------------------------------------
// PREP (merged): blocks 0..2047 = layer-1 (K=8) -> h1 bf16 hi/lo [2048x1024,
// K-padded]; blocks 2048..3455 = weight conversion W2 -> [1024x1024] hi/lo,
// W3 -> [384x1024] hi/lo, all zero-padded.  (identical to r16/r17)
// ---------------------------------------------------------------------------
__global__ __launch_bounds__(256)
void prep_kernel(const float* __restrict__ G, const float* __restrict__ W1,
                 const float* __restrict__ bias, const float* __restrict__ gamma,
                 const float* __restrict__ beta, const float* __restrict__ mean,
                 const float* __restrict__ var,
                 const float* __restrict__ W2, const float* __restrict__ W3,
                 short* __restrict__ h1h, short* __restrict__ h1l,
                 short* __restrict__ W2h, short* __restrict__ W2l,
                 short* __restrict__ W3h, short* __restrict__ W3l)
{
    const int bid = blockIdx.x;
    const int t = threadIdx.x;
    if (bid < 2048) {
        const int m = bid;
        const int n = 4 * t;
        short4 hh = {0,0,0,0}, ll = {0,0,0,0};
        if (t < 250) {
            float4 g0 = *(const float4*)(G + (size_t)m * 8 + 0);
            float4 g1 = *(const float4*)(G + (size_t)m * 8 + 4);
            float4 bi = *(const float4*)(bias + n);
            float4 ga = *(const float4*)(gamma + n);
            float4 be = *(const float4*)(beta + n);
            float4 mu = *(const float4*)(mean + n);
            float4 va = *(const float4*)(var + n);
            float y[4];
            const float* bip = &bi.x; const float* gap = &ga.x; const float* bep = &be.x;
            const float* mup = &mu.x; const float* vap = &va.x;
#pragma unroll
            for (int j = 0; j < 4; ++j) {
                const float* wp = W1 + (size_t)(n + j) * 8;
                float4 w0 = *(const float4*)(wp + 0);
                float4 w1 = *(const float4*)(wp + 4);
                float d = g0.x*w0.x + g0.y*w0.y + g0.z*w0.z + g0.w*w0.w
                        + g1.x*w1.x + g1.y*w1.y + g1.z*w1.z + g1.w*w1.w;
                float s  = gap[j] * rsqrtf(vap[j] + BN_EPS_F);
                float t0 = fmaf(s, bip[j] - mup[j], bep[j]);
                y[j] = fmaxf(fmaf(s, d, t0), 0.f);
            }
            split2(y[0], hh.x, ll.x); split2(y[1], hh.y, ll.y);
            split2(y[2], hh.z, ll.z); split2(y[3], hh.w, ll.w);
        }
        *(short4*)&h1h[(size_t)m * 1024 + n] = hh;
        *(short4*)&h1l[(size_t)m * 1024 + n] = ll;
    } else {
        const int row = bid - 2048;          // 0..1407
        const int c = 4 * t;
        short4 hh = {0,0,0,0}, ll = {0,0,0,0};
        if (row < 1024) {
            if (row < 1000 && c < 1000) {
                float4 v = *(const float4*)(W2 + (size_t)row * 1000 + c);
                split2(v.x, hh.x, ll.x); split2(v.y, hh.y, ll.y);
                split2(v.z, hh.z, ll.z); split2(v.w, hh.w, ll.w);
            }
            *(short4*)&W2h[(size_t)row * 1024 + c] = hh;
            *(short4*)&W2l[(size_t)row * 1024 + c] = ll;
        } else {
            const int r = row - 1024;        // 0..383
            if (r < 300 && c < 1000) {
                float4 v = *(const float4*)(W3 + (size_t)r * 1000 + c);
                split2(v.x, hh.x, ll.x); split2(v.y, hh.y, ll.y);
                split2(v.z, hh.z, ll.z); split2(v.w, hh.w, ll.w);
            }
            *(short4*)&W3h[(size_t)r * 1024 + c] = hh;
            *(short4*)&W3l[(size_t)r * 1024 + c] = ll;
        }
    }
}

// ---------------------------------------------------------------------------
// Split-bf16 MFMA NT GEMM, 8-wave (512 thr), 128Mx64N tile, BK=64,
// A-DIRECT (r18): each lane loads its A fragments straight from global
// (16 full 64B lines per instr, L2-resident), 1-step register prefetch with
// NAMED register sets (static indexing). Only B goes through LDS (36 KB,
// double-buffered, single barrier per step, 2-deep global prefetch — the
// r17-proven shape). Waves in 4M x 2N grid: wave = 32Mx32N = 2x2 mfma tiles.
// LDS per K=64 step per CU: 64 frag reads + 16 staging writes (~960 cyc) vs
// r17's 128 reads + 48 writes (~2100 cyc).
// MODE 0: BN+relu+split2 -> bf16 hi/lo. MODE 2: raw f32 partial (split-K z).
// Requires kchunk >= 128, kchunk % 64 == 0. A,B bf16 [rows x 1024] K-padded.
// ---------------------------------------------------------------------------
template<int MODE>
__global__ __launch_bounds__(512)
void gemm_ad8(const short* __restrict__ Ah, const short* __restrict__ Al,
              const short* __restrict__ Bh, const short* __restrict__ Bl,
              int kchunk,
              const float* __restrict__ bias, const float* __restrict__ gamma,
              const float* __restrict__ beta, const float* __restrict__ mean,
              const float* __restrict__ var,
              short* __restrict__ Ch, short* __restrict__ Cl,
              float* __restrict__ Cp, int ldc, size_t zstride)
{
    __shared__ short LBh[2][64][72], LBl[2][64][72];   // B only: 36 KB

    const int tid  = threadIdx.x;
    const int w    = tid >> 6, lane = tid & 63;
    const int wm   = w >> 1, wn = w & 1;      // 4M x 2N wave grid
    const int fr   = lane & 15, fq = lane >> 4;
    const int m0   = blockIdx.y * 128;
    const int n0   = blockIdx.x * 64;
    const int z    = blockIdx.z;
    const int ks   = z * kchunk;
    const int nt   = kchunk >> 6;             // K-steps of 64

    // ---- A direct-from-global: lane-private fragment base ----
    // fragment (mi, slice s) at offset mi*16*1024 + s*32 + kt
    const short* gA0h = Ah + (size_t)(m0 + wm*32 + fr) * 1024 + fq * 8;
    const short* gA0l = Al + (size_t)(m0 + wm*32 + fr) * 1024 + fq * 8;

    // ---- B staging: threads 0..255 -> 64 rows x 64 shorts (2 int4 each) ----
    const bool doB = tid < 256;
    const int brow = tid >> 2;                // 0..63 when doB
    const int boff = (tid & 3) * 16;
    const short* gBh = Bh + (size_t)(n0 + (brow & 63)) * 1024 + boff;
    const short* gBl = Bl + (size_t)(n0 + (brow & 63)) * 1024 + boff;

    int4 pbh0, pbh1, pbl0, pbl1;

    // A fragment registers: current + next, named (static indexing, rule #20).
    // index: [slice s][tile mi] flattened: s0m0, s0m1, s1m0, s1m1
    short8v cah00, cah01, cah10, cah11, cal00, cal01, cal10, cal11;
    short8v nah00, nah01, nah10, nah11, nal00, nal01, nal10, nal11;

    floatx4 acc[2][2];
#pragma unroll
    for (int i = 0; i < 2; ++i)
#pragma unroll
        for (int j = 0; j < 2; ++j) acc[i][j] = (floatx4){0.f,0.f,0.f,0.f};

#define GLOADB(KT) do {                                                       \
    const int kt_ = (KT);                                                     \
    pbh0 = *(const int4*)(gBh + kt_);                                         \
    pbh1 = *(const int4*)(gBh + kt_ + 8);                                     \
    pbl0 = *(const int4*)(gBl + kt_);                                         \
    pbl1 = *(const int4*)(gBl + kt_ + 8);                                     \
} while (0)

#define LWRITEB(BUF) do {                                                     \
    if (doB) {                                                                \
        *(int4*)&LBh[BUF][brow][boff]     = pbh0;                             \
        *(int4*)&LBh[BUF][brow][boff + 8] = pbh1;                             \
        *(int4*)&LBl[BUF][brow][boff]     = pbl0;                             \
        *(int4*)&LBl[BUF][brow][boff + 8] = pbl1;                             \
    }                                                                         \
} while (0)

#define GLOADA(KT, H00,H01,H10,H11, L00,L01,L10,L11) do {                     \
    const int kt_ = (KT);                                                     \
    H00 = *(const short8v*)(gA0h + kt_);                                      \
    H01 = *(const short8v*)(gA0h + 16*1024 + kt_);                            \
    H10 = *(const short8v*)(gA0h + kt_ + 32);                                 \
    H11 = *(const short8v*)(gA0h + 16*1024 + kt_ + 32);                       \
    L00 = *(const short8v*)(gA0l + kt_);                                      \
    L01 = *(const short8v*)(gA0l + 16*1024 + kt_);                            \
    L10 = *(const short8v*)(gA0l + kt_ + 32);                                 \
    L11 = *(const short8v*)(gA0l + 16*1024 + kt_ + 32);                       \
} while (0)

#define MFMA_SLICE(BUF, KO, AH0, AH1, AL0, AL1) do {                          \
    short8v bh_[2], bl_[2];                                                   \
    _Pragma("unroll")                                                         \
    for (int nj = 0; nj < 2; ++nj) {                                          \
        bh_[nj] = *(const short8v*)&LBh[BUF][wn*32 + nj*16 + fr][KO];         \
        bl_[nj] = *(const short8v*)&LBl[BUF][wn*32 + nj*16 + fr][KO];         \
    }                                                                         \
    _Pragma("unroll")                                                         \
    for (int nj = 0; nj < 2; ++nj) {                                          \
        acc[0][nj] = __builtin_amdgcn_mfma_f32_16x16x32_bf16(AH0, bh_[nj], acc[0][nj], 0, 0, 0); \
        acc[0][nj] = __builtin_amdgcn_mfma_f32_16x16x32_bf16(AH0, bl_[nj], acc[0][nj], 0, 0, 0); \
        acc[0][nj] = __builtin_amdgcn_mfma_f32_16x16x32_bf16(AL0, bh_[nj], acc[0][nj], 0, 0, 0); \
        acc[1][nj] = __builtin_amdgcn_mfma_f32_16x16x32_bf16(AH1, bh_[nj], acc[1][nj], 0, 0, 0); \
        acc[1][nj] = __builtin_amdgcn_mfma_f32_16x16x32_bf16(AH1, bl_[nj], acc[1][nj], 0, 0, 0); \
        acc[1][nj] = __builtin_amdgcn_mfma_f32_16x16x32_bf16(AL1, bh_[nj], acc[1][nj], 0, 0, 0); \
    }                                                                         \
} while (0)

    // prologue (nt >= 2 guaranteed by callers)
    GLOADA(ks, cah00,cah01,cah10,cah11, cal00,cal01,cal10,cal11);
    GLOADB(ks);
    LWRITEB(0);
    GLOADB(ks + 64);
    __syncthreads();

    const int kq = fq * 8;

    for (int t = 0; t < nt; ++t) {
        const int cur = t & 1;

        if (t + 1 < nt)
            GLOADA(ks + (t + 1) * 64, nah00,nah01,nah10,nah11,
                                      nal00,nal01,nal10,nal11);

        MFMA_SLICE(cur, kq,      cah00, cah01, cal00, cal01);   // slice 0
        MFMA_SLICE(cur, 32 + kq, cah10, cah11, cal10, cal11);   // slice 1

        if (t + 1 < nt) {
            LWRITEB(cur ^ 1);                      // disjoint from buf cur
            if (t + 2 < nt) GLOADB(ks + (t + 2) * 64);
            __syncthreads();                       // buf cur^1 ready for t+1
            cah00 = nah00; cah01 = nah01; cah10 = nah10; cah11 = nah11;
            cal00 = nal00; cal01 = nal01; cal10 = nal10; cal11 = nal11;
        }
    }
#undef GLOADB
#undef LWRITEB
#undef GLOADA
#undef MFMA_SLICE

    // ---- epilogue (D: col=lane&15, row=(lane>>4)*4+r) ----
    if (MODE == 0) {
        float s[2], t0[2];
#pragma unroll
        for (int nj = 0; nj < 2; ++nj) {
            const int col = n0 + wn*32 + nj*16 + fr;
            if (col < 1000) {
                const float sg = gamma[col] * rsqrtf(var[col] + BN_EPS_F);
                s[nj]  = sg;
                t0[nj] = fmaf(sg, bias[col] - mean[col], beta[col]);
            } else { s[nj] = 0.f; t0[nj] = 0.f; }
        }
#pragma unroll
        for (int mi = 0; mi < 2; ++mi) {
            const int rbase = m0 + wm*32 + mi*16 + fq*4;
#pragma unroll
            for (int nj = 0; nj < 2; ++nj) {
                const int col = n0 + wn*32 + nj*16 + fr;
#pragma unroll
                for (int r = 0; r < 4; ++r) {
                    const float y = fmaxf(fmaf(s[nj], acc[mi][nj][r], t0[nj]), 0.f);
                    short h, l; split2(y, h, l);
                    Ch[(size_t)(rbase + r) * 1024 + col] = h;
                    Cl[(size_t)(rbase + r) * 1024 + col] = l;
                }
            }
        }
    } else {
        float* Cz = Cp + (size_t)z * zstride;
#pragma unroll
        for (int mi = 0; mi < 2; ++mi) {
            const int rbase = m0 + wm*32 + mi*16 + fq*4;
#pragma unroll
            for (int nj = 0; nj < 2; ++nj) {
                const int col = n0 + wn*32 + nj*16 + fr;
#pragma unroll
                for (int r = 0; r < 4; ++r)
                    Cz[(size_t)(rbase + r) * ldc + col] = acc[mi][nj][r];
            }
        }
    }
}

// ---------------------------------------------------------------------------
// FUSED: split-K2 reduce for layer 3 + BN + sigmoid + Lorentz spectrum.
// part3: 2 panels, ld 384.  (identical to r16/r17)
// ---------------------------------------------------------------------------
__global__ __launch_bounds__(320)
void lorentz_fused(const float* __restrict__ part, size_t pstride,
                   const float* __restrict__ bias, const float* __restrict__ gamma,
                   const float* __restrict__ beta, const float* __restrict__ mean,
                   const float* __restrict__ var,
                   const float* __restrict__ G,     // 2048 x 8
                   const float* __restrict__ wgrid, // 300
                   float* __restrict__ T)           // 2048 x 300
{
    __shared__ float  s_p[304];
    __shared__ float4 s_pk[100];   // {w0^2, wp^2, wp^2*g, g^2}
    const int b   = blockIdx.x;
    const int tid = threadIdx.x;

    if (tid < 300) {
        const size_t off = (size_t)b * 384 + tid;
        float d = part[off] + part[pstride + off];
        const float s = gamma[tid] * rsqrtf(var[tid] + BN_EPS_F);
        const float y = fmaf(s, d + bias[tid] - mean[tid], beta[tid]);
        s_p[tid] = 1.f / (1.f + expf(-y));
    }
    __syncthreads();
    if (tid < 100) {
        const float w0 = s_p[3*tid    ] * 5.f;
        const float wp = s_p[3*tid + 1] * 5.f;
        const float g  = s_p[3*tid + 2] * 0.5f;
        s_pk[tid] = make_float4(w0*w0, wp*wp, wp*wp*g, g*g);
    }
    __syncthreads();
    if (tid < 300) {
        const float wg = wgrid[tid];
        const float w2 = wg*wg;
        float e1 = 0.f, e2s = 0.f;
#pragma unroll 10
        for (int l = 0; l < 100; ++l) {
            const float4 v    = s_pk[l];
            const float s1    = v.x - w2;
            const float denom = fmaf(s1, s1, w2 * v.w);
            const float r     = __builtin_amdgcn_rcpf(denom);
            e1  = fmaf(v.y*s1, r, e1);
            e2s = fmaf(v.z,    r, e2s);
        }
        e1 += 10.f;
        const float e2  = e2s * wg;
        const float mag = sqrtf(fmaf(e1, e1, e2*e2));
        const float nn  = sqrtf(0.5f*(mag + e1));
        const float kk  = sqrtf(fmaxf(0.5f*(mag - e1), 0.f));
        const float d   = fmaxf(fmaxf(G[b*8+4], G[b*8+5]),
                                fmaxf(G[b*8+6], G[b*8+7]));
        const float ab  = expf(-0.006283185307179586f * d * kk);
        const float np1 = nn + 1.f;
        const float Tv  = 4.f*nn / fmaf(np1, np1, kk*kk) * ab;
        T[(size_t)b*300 + tid] = Tv;
    }
}

extern "C" void kernel_launch(void* const* d_in, const int* in_sizes, int n_in,
                              void* d_out, int out_size, void* d_ws, size_t ws_size,
                              hipStream_t stream) {
    const float* G      = (const float*)d_in[0];
    const float* W1     = (const float*)d_in[1];
    const float* b1     = (const float*)d_in[2];
    const float* gamma1 = (const float*)d_in[3];
    const float* beta1  = (const float*)d_in[4];
    const float* mean1  = (const float*)d_in[5];
    const float* var1   = (const float*)d_in[6];
    const float* W2     = (const float*)d_in[7];
    const float* b2     = (const float*)d_in[8];
    const float* gamma2 = (const float*)d_in[9];
    const float* beta2  = (const float*)d_in[10];
    const float* mean2  = (const float*)d_in[11];
    const float* var2   = (const float*)d_in[12];
    const float* W3     = (const float*)d_in[13];
    const float* b3     = (const float*)d_in[14];
    const float* gamma3 = (const float*)d_in[15];
    const float* beta3  = (const float*)d_in[16];
    const float* mean3  = (const float*)d_in[17];
    const float* var3   = (const float*)d_in[18];
    const float* wgrid  = (const float*)d_in[19];

    char*  wsb = (char*)d_ws;
    float* T   = (float*)d_out;

    // Layout, 28.8 MB total (ws >= 41 MB proven by round-10 big path):
    //   h1h   @ [0          ..  4,194,304)   2048x1024 bf16
    //   h1l   @ [4,194,304  ..  8,388,608)
    //   W2h   @ [8,388,608  .. 10,485,760)   1024x1024 bf16
    //   W2l   @ [10,485,760 .. 12,582,912)
    //   h2h   @ [12,582,912 .. 16,777,216)   2048x1024 bf16
    //   h2l   @ [16,777,216 .. 20,971,520)
    //   W3h   @ [20,971,520 .. 21,757,952)   384x1024 bf16
    //   W3l   @ [21,757,952 .. 22,544,384)
    //   part3 @ [22,544,384 .. 28,835,840)   2 x 2048x384 f32
    short* h1h   = (short*)(wsb);
    short* h1l   = (short*)(wsb + 4194304);
    short* W2h   = (short*)(wsb + 8388608);
    short* W2l   = (short*)(wsb + 10485760);
    short* h2h   = (short*)(wsb + 12582912);
    short* h2l   = (short*)(wsb + 16777216);
    short* W3h   = (short*)(wsb + 20971520);
    short* W3l   = (short*)(wsb + 21757952);
    float* part3 = (float*)(wsb + 22544384);

    // PREP: layer 1 + weight conversions (merged, independent sections)
    prep_kernel<<<3456, 256, 0, stream>>>(G, W1, b1, gamma1, beta1, mean1, var1,
                                          W2, W3, h1h, h1l, W2h, W2l, W3h, W3l);

    // Layer 2: fused MFMA GEMM (A-direct, 8-wave) + BN + relu + split -> h2
    // grid (16n,16m) = 256 blocks x 8 waves = 8 waves/CU (2/SIMD)
    gemm_ad8<0><<<dim3(16, 16), 512, 0, stream>>>(
        h1h, h1l, W2h, W2l, 1024, b2, gamma2, beta2, mean2, var2,
        h2h, h2l, nullptr, 0, 0);

    // Layer 3: raw partials, split-K=2 (grid 6n x 16m x 2z = 192 blocks)
    gemm_ad8<2><<<dim3(6, 16, 2), 512, 0, stream>>>(
        h2h, h2l, W3h, W3l, 512, nullptr, nullptr, nullptr, nullptr, nullptr,
        nullptr, nullptr, part3, 384, (size_t)786432);

    // Fused reduce3 + BN + sigmoid + Lorentz spectrum -> T
    lorentz_fused<<<2048, 320, 0, stream>>>(part3, (size_t)786432,
        b3, gamma3, beta3, mean3, var3, G, wgrid, T);
}

// Round 19
// 66.772 us; speedup vs baseline: 1.4768x; 1.4768x over previous
//
#include <hip/hip_runtime.h>
#include <hip/hip_bf16.h>
#include <math.h>

#define BN_EPS_F 1e-5f

typedef __attribute__((ext_vector_type(8))) short short8v;   // 8 bf16 = 4 VGPR
typedef __attribute__((ext_vector_type(4))) float floatx4;   // MFMA C/D

// split fp32 -> bf16 hi + bf16 lo  (x ~= hi + lo, rel err ~2^-17)
__device__ __forceinline__ void split2(float x, short& h, short& l) {
    __hip_bfloat16 bh = __float2bfloat16(x);
    float hf = __bfloat162float(bh);
    __hip_bfloat16 bl = __float2bfloat16(x - hf);
    h = __builtin_bit_cast(short, bh);
    l = __builtin_bit_cast(short, bl);
}

// ---------------------------------------------------------------------------
// PREP (merged): blocks 0..2047 = layer-1 (K=8) -> h1 bf16 hi/lo [2048x1024,
// K-padded]; blocks 2048..3455 = weight conversion W2 -> [1024x1024] hi/lo,
// W3 -> [384x1024] hi/lo, all zero-padded.  (identical to r16/r17)
// ---------------------------------------------------------------------------
__global__ __launch_bounds__(256)
void prep_kernel(const float* __restrict__ G, const float* __restrict__ W1,
                 const float* __restrict__ bias, const float* __restrict__ gamma,
                 const float* __restrict__ beta, const float* __restrict__ mean,
                 const float* __restrict__ var,
                 const float* __restrict__ W2, const float* __restrict__ W3,
                 short* __restrict__ h1h, short* __restrict__ h1l,
                 short* __restrict__ W2h, short* __restrict__ W2l,
                 short* __restrict__ W3h, short* __restrict__ W3l)
{
    const int bid = blockIdx.x;
    const int t = threadIdx.x;
    if (bid < 2048) {
        const int m = bid;
        const int n = 4 * t;
        short4 hh = {0,0,0,0}, ll = {0,0,0,0};
        if (t < 250) {
            float4 g0 = *(const float4*)(G + (size_t)m * 8 + 0);
            float4 g1 = *(const float4*)(G + (size_t)m * 8 + 4);
            float4 bi = *(const float4*)(bias + n);
            float4 ga = *(const float4*)(gamma + n);
            float4 be = *(const float4*)(beta + n);
            float4 mu = *(const float4*)(mean + n);
            float4 va = *(const float4*)(var + n);
            float y[4];
            const float* bip = &bi.x; const float* gap = &ga.x; const float* bep = &be.x;
            const float* mup = &mu.x; const float* vap = &va.x;
#pragma unroll
            for (int j = 0; j < 4; ++j) {
                const float* wp = W1 + (size_t)(n + j) * 8;
                float4 w0 = *(const float4*)(wp + 0);
                float4 w1 = *(const float4*)(wp + 4);
                float d = g0.x*w0.x + g0.y*w0.y + g0.z*w0.z + g0.w*w0.w
                        + g1.x*w1.x + g1.y*w1.y + g1.z*w1.z + g1.w*w1.w;
                float s  = gap[j] * rsqrtf(vap[j] + BN_EPS_F);
                float t0 = fmaf(s, bip[j] - mup[j], bep[j]);
                y[j] = fmaxf(fmaf(s, d, t0), 0.f);
            }
            split2(y[0], hh.x, ll.x); split2(y[1], hh.y, ll.y);
            split2(y[2], hh.z, ll.z); split2(y[3], hh.w, ll.w);
        }
        *(short4*)&h1h[(size_t)m * 1024 + n] = hh;
        *(short4*)&h1l[(size_t)m * 1024 + n] = ll;
    } else {
        const int row = bid - 2048;          // 0..1407
        const int c = 4 * t;
        short4 hh = {0,0,0,0}, ll = {0,0,0,0};
        if (row < 1024) {
            if (row < 1000 && c < 1000) {
                float4 v = *(const float4*)(W2 + (size_t)row * 1000 + c);
                split2(v.x, hh.x, ll.x); split2(v.y, hh.y, ll.y);
                split2(v.z, hh.z, ll.z); split2(v.w, hh.w, ll.w);
            }
            *(short4*)&W2h[(size_t)row * 1024 + c] = hh;
            *(short4*)&W2l[(size_t)row * 1024 + c] = ll;
        } else {
            const int r = row - 1024;        // 0..383
            if (r < 300 && c < 1000) {
                float4 v = *(const float4*)(W3 + (size_t)r * 1000 + c);
                split2(v.x, hh.x, ll.x); split2(v.y, hh.y, ll.y);
                split2(v.z, hh.z, ll.z); split2(v.w, hh.w, ll.w);
            }
            *(short4*)&W3h[(size_t)r * 1024 + c] = hh;
            *(short4*)&W3l[(size_t)r * 1024 + c] = ll;
        }
    }
}

// ---------------------------------------------------------------------------
// Split-bf16 MFMA NT GEMM — r17-proven structure (68.7 µs config), verbatim,
// plus s_setprio(1) around the MFMA slices (T5: pays when waves have role
// diversity — here waves 0-3 also stage B, 4-7 don't).
// 8 waves (512 thr), 128Mx64N tile, BK=64, dbuf LDS (108 KB), waves 4Mx2N
// (wave = 32Mx32N = 2x2 mfma tiles): 8 ds_read_b128 per 12 MFMA per slice.
// Single barrier per step + 2-deep global prefetch.
// MODE 0: BN+relu+split2 -> bf16 hi/lo. MODE 2: raw f32 partial (split-K z).
// Requires kchunk >= 128, kchunk % 64 == 0.
// ---------------------------------------------------------------------------
template<int MODE>
__global__ __launch_bounds__(512)
void gemm8w(const short* __restrict__ Ah, const short* __restrict__ Al,
            const short* __restrict__ Bh, const short* __restrict__ Bl,
            int kchunk,
            const float* __restrict__ bias, const float* __restrict__ gamma,
            const float* __restrict__ beta, const float* __restrict__ mean,
            const float* __restrict__ var,
            short* __restrict__ Ch, short* __restrict__ Cl,
            float* __restrict__ Cp, int ldc, size_t zstride)
{
    __shared__ short LAh[2][128][72], LAl[2][128][72];   // 128 rows x 64 K (+8 pad)
    __shared__ short LBh[2][64][72],  LBl[2][64][72];    // 64 rows x 64 K

    const int tid  = threadIdx.x;
    const int w    = tid >> 6, lane = tid & 63;
    const int wm   = w >> 1, wn = w & 1;      // 4M x 2N wave grid
    const int fr   = lane & 15, fq = lane >> 4;
    const int m0   = blockIdx.y * 128;
    const int n0   = blockIdx.x * 64;
    const int z    = blockIdx.z;
    const int ks   = z * kchunk;
    const int nt   = kchunk >> 6;             // K-steps of 64

    // A staging: 512 thr -> 128 rows x 64 shorts: row=tid>>2, 2 int4 at (tid&3)*16
    const int arow = tid >> 2;
    const int aoff = (tid & 3) * 16;
    // B staging: threads 0..255 -> 64 rows x 64 shorts: row=tid>>2, 2 int4
    const bool doB = tid < 256;
    const int brow = tid >> 2;                // valid when doB (0..63)
    const int boff = (tid & 3) * 16;

    const short* gAh = Ah + (size_t)(m0 + arow) * 1024 + aoff;
    const short* gAl = Al + (size_t)(m0 + arow) * 1024 + aoff;
    const short* gBh = Bh + (size_t)(n0 + (brow & 63)) * 1024 + boff;
    const short* gBl = Bl + (size_t)(n0 + (brow & 63)) * 1024 + boff;

    int4 pah0, pah1, pal0, pal1, pbh0, pbh1, pbl0, pbl1;

    floatx4 acc[2][2];
#pragma unroll
    for (int i = 0; i < 2; ++i)
#pragma unroll
        for (int j = 0; j < 2; ++j) acc[i][j] = (floatx4){0.f,0.f,0.f,0.f};

#define GLOAD(KT) do {                                                        \
    const int kt_ = (KT);                                                     \
    pah0 = *(const int4*)(gAh + kt_);                                         \
    pah1 = *(const int4*)(gAh + kt_ + 8);                                     \
    pal0 = *(const int4*)(gAl + kt_);                                         \
    pal1 = *(const int4*)(gAl + kt_ + 8);                                     \
    if (doB) {                                                                \
        pbh0 = *(const int4*)(gBh + kt_);                                     \
        pbh1 = *(const int4*)(gBh + kt_ + 8);                                 \
        pbl0 = *(const int4*)(gBl + kt_);                                     \
        pbl1 = *(const int4*)(gBl + kt_ + 8);                                 \
    }                                                                         \
} while (0)

#define LWRITE(BUF) do {                                                      \
    *(int4*)&LAh[BUF][arow][aoff]     = pah0;                                 \
    *(int4*)&LAh[BUF][arow][aoff + 8] = pah1;                                 \
    *(int4*)&LAl[BUF][arow][aoff]     = pal0;                                 \
    *(int4*)&LAl[BUF][arow][aoff + 8] = pal1;                                 \
    if (doB) {                                                                \
        *(int4*)&LBh[BUF][brow][boff]     = pbh0;                             \
        *(int4*)&LBh[BUF][brow][boff + 8] = pbh1;                             \
        *(int4*)&LBl[BUF][brow][boff]     = pbl0;                             \
        *(int4*)&LBl[BUF][brow][boff + 8] = pbl1;                             \
    }                                                                         \
} while (0)

    // prologue (nt >= 2 guaranteed by callers)
    GLOAD(ks);
    LWRITE(0);
    GLOAD(ks + 64);
    __syncthreads();

    const int kq = fq * 8;

    for (int t = 0; t < nt; ++t) {
        const int cur = t & 1;

#pragma unroll
        for (int s = 0; s < 2; ++s) {          // two K=32 slices of the BK=64 step
            const int ko = s * 32 + kq;
            short8v ah[2], al[2], bh[2], bl[2];
#pragma unroll
            for (int mi = 0; mi < 2; ++mi) {
                ah[mi] = *(const short8v*)&LAh[cur][wm*32 + mi*16 + fr][ko];
                al[mi] = *(const short8v*)&LAl[cur][wm*32 + mi*16 + fr][ko];
            }
#pragma unroll
            for (int nj = 0; nj < 2; ++nj) {
                bh[nj] = *(const short8v*)&LBh[cur][wn*32 + nj*16 + fr][ko];
                bl[nj] = *(const short8v*)&LBl[cur][wn*32 + nj*16 + fr][ko];
            }
            __builtin_amdgcn_s_setprio(1);
#pragma unroll
            for (int mi = 0; mi < 2; ++mi)
#pragma unroll
                for (int nj = 0; nj < 2; ++nj) {
                    acc[mi][nj] = __builtin_amdgcn_mfma_f32_16x16x32_bf16(
                                      ah[mi], bh[nj], acc[mi][nj], 0, 0, 0);
                    acc[mi][nj] = __builtin_amdgcn_mfma_f32_16x16x32_bf16(
                                      ah[mi], bl[nj], acc[mi][nj], 0, 0, 0);
                    acc[mi][nj] = __builtin_amdgcn_mfma_f32_16x16x32_bf16(
                                      al[mi], bh[nj], acc[mi][nj], 0, 0, 0);
                }
            __builtin_amdgcn_s_setprio(0);
        }

        if (t + 1 < nt) {
            LWRITE(cur ^ 1);                       // disjoint from buf cur
            if (t + 2 < nt) GLOAD(ks + (t + 2) * 64);
            __syncthreads();                       // buf cur^1 ready for t+1
        }
    }
#undef GLOAD
#undef LWRITE

    // ---- epilogue (D: col=lane&15, row=(lane>>4)*4+r) ----
    if (MODE == 0) {
        float s[2], t0[2];
#pragma unroll
        for (int nj = 0; nj < 2; ++nj) {
            const int col = n0 + wn*32 + nj*16 + fr;
            if (col < 1000) {
                const float sg = gamma[col] * rsqrtf(var[col] + BN_EPS_F);
                s[nj]  = sg;
                t0[nj] = fmaf(sg, bias[col] - mean[col], beta[col]);
            } else { s[nj] = 0.f; t0[nj] = 0.f; }
        }
#pragma unroll
        for (int mi = 0; mi < 2; ++mi) {
            const int rbase = m0 + wm*32 + mi*16 + fq*4;
#pragma unroll
            for (int nj = 0; nj < 2; ++nj) {
                const int col = n0 + wn*32 + nj*16 + fr;
#pragma unroll
                for (int r = 0; r < 4; ++r) {
                    const float y = fmaxf(fmaf(s[nj], acc[mi][nj][r], t0[nj]), 0.f);
                    short h, l; split2(y, h, l);
                    Ch[(size_t)(rbase + r) * 1024 + col] = h;
                    Cl[(size_t)(rbase + r) * 1024 + col] = l;
                }
            }
        }
    } else {
        float* Cz = Cp + (size_t)z * zstride;
#pragma unroll
        for (int mi = 0; mi < 2; ++mi) {
            const int rbase = m0 + wm*32 + mi*16 + fq*4;
#pragma unroll
            for (int nj = 0; nj < 2; ++nj) {
                const int col = n0 + wn*32 + nj*16 + fr;
#pragma unroll
                for (int r = 0; r < 4; ++r)
                    Cz[(size_t)(rbase + r) * ldc + col] = acc[mi][nj][r];
            }
        }
    }
}

// ---------------------------------------------------------------------------
// FUSED: split-K2 reduce for layer 3 + BN + sigmoid + Lorentz spectrum.
// part3: 2 panels, ld 384.  (identical to r16/r17)
// ---------------------------------------------------------------------------
__global__ __launch_bounds__(320)
void lorentz_fused(const float* __restrict__ part, size_t pstride,
                   const float* __restrict__ bias, const float* __restrict__ gamma,
                   const float* __restrict__ beta, const float* __restrict__ mean,
                   const float* __restrict__ var,
                   const float* __restrict__ G,     // 2048 x 8
                   const float* __restrict__ wgrid, // 300
                   float* __restrict__ T)           // 2048 x 300
{
    __shared__ float  s_p[304];
    __shared__ float4 s_pk[100];   // {w0^2, wp^2, wp^2*g, g^2}
    const int b   = blockIdx.x;
    const int tid = threadIdx.x;

    if (tid < 300) {
        const size_t off = (size_t)b * 384 + tid;
        float d = part[off] + part[pstride + off];
        const float s = gamma[tid] * rsqrtf(var[tid] + BN_EPS_F);
        const float y = fmaf(s, d + bias[tid] - mean[tid], beta[tid]);
        s_p[tid] = 1.f / (1.f + expf(-y));
    }
    __syncthreads();
    if (tid < 100) {
        const float w0 = s_p[3*tid    ] * 5.f;
        const float wp = s_p[3*tid + 1] * 5.f;
        const float g  = s_p[3*tid + 2] * 0.5f;
        s_pk[tid] = make_float4(w0*w0, wp*wp, wp*wp*g, g*g);
    }
    __syncthreads();
    if (tid < 300) {
        const float wg = wgrid[tid];
        const float w2 = wg*wg;
        float e1 = 0.f, e2s = 0.f;
#pragma unroll 10
        for (int l = 0; l < 100; ++l) {
            const float4 v    = s_pk[l];
            const float s1    = v.x - w2;
            const float denom = fmaf(s1, s1, w2 * v.w);
            const float r     = __builtin_amdgcn_rcpf(denom);
            e1  = fmaf(v.y*s1, r, e1);
            e2s = fmaf(v.z,    r, e2s);
        }
        e1 += 10.f;
        const float e2  = e2s * wg;
        const float mag = sqrtf(fmaf(e1, e1, e2*e2));
        const float nn  = sqrtf(0.5f*(mag + e1));
        const float kk  = sqrtf(fmaxf(0.5f*(mag - e1), 0.f));
        const float d   = fmaxf(fmaxf(G[b*8+4], G[b*8+5]),
                                fmaxf(G[b*8+6], G[b*8+7]));
        const float ab  = expf(-0.006283185307179586f * d * kk);
        const float np1 = nn + 1.f;
        const float Tv  = 4.f*nn / fmaf(np1, np1, kk*kk) * ab;
        T[(size_t)b*300 + tid] = Tv;
    }
}

extern "C" void kernel_launch(void* const* d_in, const int* in_sizes, int n_in,
                              void* d_out, int out_size, void* d_ws, size_t ws_size,
                              hipStream_t stream) {
    const float* G      = (const float*)d_in[0];
    const float* W1     = (const float*)d_in[1];
    const float* b1     = (const float*)d_in[2];
    const float* gamma1 = (const float*)d_in[3];
    const float* beta1  = (const float*)d_in[4];
    const float* mean1  = (const float*)d_in[5];
    const float* var1   = (const float*)d_in[6];
    const float* W2     = (const float*)d_in[7];
    const float* b2     = (const float*)d_in[8];
    const float* gamma2 = (const float*)d_in[9];
    const float* beta2  = (const float*)d_in[10];
    const float* mean2  = (const float*)d_in[11];
    const float* var2   = (const float*)d_in[12];
    const float* W3     = (const float*)d_in[13];
    const float* b3     = (const float*)d_in[14];
    const float* gamma3 = (const float*)d_in[15];
    const float* beta3  = (const float*)d_in[16];
    const float* mean3  = (const float*)d_in[17];
    const float* var3   = (const float*)d_in[18];
    const float* wgrid  = (const float*)d_in[19];

    char*  wsb = (char*)d_ws;
    float* T   = (float*)d_out;

    // Layout, 28.8 MB total (ws >= 41 MB proven by round-10 big path):
    //   h1h   @ [0          ..  4,194,304)   2048x1024 bf16
    //   h1l   @ [4,194,304  ..  8,388,608)
    //   W2h   @ [8,388,608  .. 10,485,760)   1024x1024 bf16
    //   W2l   @ [10,485,760 .. 12,582,912)
    //   h2h   @ [12,582,912 .. 16,777,216)   2048x1024 bf16
    //   h2l   @ [16,777,216 .. 20,971,520)
    //   W3h   @ [20,971,520 .. 21,757,952)   384x1024 bf16
    //   W3l   @ [21,757,952 .. 22,544,384)
    //   part3 @ [22,544,384 .. 28,835,840)   2 x 2048x384 f32
    short* h1h   = (short*)(wsb);
    short* h1l   = (short*)(wsb + 4194304);
    short* W2h   = (short*)(wsb + 8388608);
    short* W2l   = (short*)(wsb + 10485760);
    short* h2h   = (short*)(wsb + 12582912);
    short* h2l   = (short*)(wsb + 16777216);
    short* W3h   = (short*)(wsb + 20971520);
    short* W3l   = (short*)(wsb + 21757952);
    float* part3 = (float*)(wsb + 22544384);

    // PREP: layer 1 + weight conversions (merged, independent sections)
    prep_kernel<<<3456, 256, 0, stream>>>(G, W1, b1, gamma1, beta1, mean1, var1,
                                          W2, W3, h1h, h1l, W2h, W2l, W3h, W3l);

    // Layer 2: fused MFMA GEMM + BN + relu + split -> h2
    // grid (16n,16m) = 256 blocks x 8 waves = 8 waves/CU (2/SIMD)
    gemm8w<0><<<dim3(16, 16), 512, 0, stream>>>(
        h1h, h1l, W2h, W2l, 1024, b2, gamma2, beta2, mean2, var2,
        h2h, h2l, nullptr, 0, 0);

    // Layer 3: raw partials, split-K=2 (grid 6n x 16m x 2z = 192 blocks)
    gemm8w<2><<<dim3(6, 16, 2), 512, 0, stream>>>(
        h2h, h2l, W3h, W3l, 512, nullptr, nullptr, nullptr, nullptr, nullptr,
        nullptr, nullptr, part3, 384, (size_t)786432);

    // Fused reduce3 + BN + sigmoid + Lorentz spectrum -> T
    lorentz_fused<<<2048, 320, 0, stream>>>(part3, (size_t)786432,
        b3, gamma3, beta3, mean3, var3, G, wgrid, T);
}